// Round 1
// baseline (1307.145 us; speedup 1.0000x reference)
//
#include <hip/hip_runtime.h>
#include <math.h>

#define NB 16384
#define DIN 2048

__device__ __forceinline__ float sigm(float v) { return 1.0f / (1.0f + expf(-v)); }

// ---------------------------------------------------------------------------
// K1: a1 = sigmoid(xt@eW1.T + eb1); dz1 = a1*(1-a1)*(xd_t@eW1.T)
// xt = [x, treatment]  (K = 2049, treatment handled as epilogue term)
// BM=32 rows, all 128 outs, 256 threads, TM=2 x TN=8 per thread.
// ---------------------------------------------------------------------------
__global__ __launch_bounds__(256) void enc1_kernel(
    const float* __restrict__ x, const float* __restrict__ xd,
    const float* __restrict__ tr, const float* __restrict__ W,
    const float* __restrict__ bias,
    float* __restrict__ a1, float* __restrict__ dz1)
{
  __shared__ float As[32 * 20];   // stride 20: 16B-aligned rows, no 4-way conflicts
  __shared__ float Ds[32 * 20];
  __shared__ float Ws[128 * 20];  // [o][k] layout
  const int t = threadIdx.x;
  const int ty = t >> 4;          // 0..15
  const int tx = t & 15;          // 0..15
  const int r0 = blockIdx.x * 32;

  float accp[2][8];
  float accg[2][8];
#pragma unroll
  for (int i = 0; i < 2; ++i)
#pragma unroll
    for (int j = 0; j < 8; ++j) { accp[i][j] = 0.f; accg[i][j] = 0.f; }

  const int row_l = t >> 3;  // 0..31 (A/D tile loads, float2 each)
  const int kp    = t & 7;   // 0..7

  for (int kt = 0; kt < 128; ++kt) {
    const int kbase = kt * 16;
    {
      const float2 av = *(const float2*)&x [(size_t)(r0 + row_l) * DIN + kbase + kp * 2];
      const float2 dv = *(const float2*)&xd[(size_t)(r0 + row_l) * DIN + kbase + kp * 2];
      As[row_l * 20 + kp * 2]     = av.x;  As[row_l * 20 + kp * 2 + 1] = av.y;
      Ds[row_l * 20 + kp * 2]     = dv.x;  Ds[row_l * 20 + kp * 2 + 1] = dv.y;
    }
#pragma unroll
    for (int i = 0; i < 8; ++i) {
      int lin = i * 256 + t;          // 0..2047
      int o = lin >> 4, k = lin & 15;
      Ws[o * 20 + k] = W[(size_t)o * 2049 + kbase + k];
    }
    __syncthreads();
#pragma unroll
    for (int k4 = 0; k4 < 4; ++k4) {
      float4 av[2], dv[2], wv[8];
#pragma unroll
      for (int i = 0; i < 2; ++i) {
        av[i] = *(const float4*)&As[(ty * 2 + i) * 20 + k4 * 4];
        dv[i] = *(const float4*)&Ds[(ty * 2 + i) * 20 + k4 * 4];
      }
#pragma unroll
      for (int j = 0; j < 8; ++j)
        wv[j] = *(const float4*)&Ws[(tx + 16 * j) * 20 + k4 * 4];
#pragma unroll
      for (int i = 0; i < 2; ++i)
#pragma unroll
        for (int j = 0; j < 8; ++j) {
          accp[i][j] = fmaf(av[i].x, wv[j].x, accp[i][j]);
          accp[i][j] = fmaf(av[i].y, wv[j].y, accp[i][j]);
          accp[i][j] = fmaf(av[i].z, wv[j].z, accp[i][j]);
          accp[i][j] = fmaf(av[i].w, wv[j].w, accp[i][j]);
          accg[i][j] = fmaf(dv[i].x, wv[j].x, accg[i][j]);
          accg[i][j] = fmaf(dv[i].y, wv[j].y, accg[i][j]);
          accg[i][j] = fmaf(dv[i].z, wv[j].z, accg[i][j]);
          accg[i][j] = fmaf(dv[i].w, wv[j].w, accg[i][j]);
        }
    }
    __syncthreads();
  }
#pragma unroll
  for (int i = 0; i < 2; ++i) {
    const int row = r0 + ty * 2 + i;
    const float trv = tr[row];
#pragma unroll
    for (int j = 0; j < 8; ++j) {
      const int o = tx + 16 * j;
      const float wlast = W[(size_t)o * 2049 + 2048];
      float p = accp[i][j] + trv * wlast + bias[o];
      float g = accg[i][j] + trv * wlast;
      float a = sigm(p);
      a1 [(size_t)row * 128 + o] = a;
      dz1[(size_t)row * 128 + o] = a * (1.f - a) * g;
    }
  }
}

// ---------------------------------------------------------------------------
// K2: encoder layers 2-4 + z, z_dot_true, z_dot_pred, loss_po/loss_tr/sindy_z
// 4 rows per block, 256 threads. All weights in LDS (padded strides).
// ---------------------------------------------------------------------------
__global__ __launch_bounds__(256) void enc_small_kernel(
    const float* __restrict__ a1, const float* __restrict__ dz1,
    const float* __restrict__ W2, const float* __restrict__ b2,
    const float* __restrict__ W3, const float* __restrict__ b3,
    const float* __restrict__ W4, const float* __restrict__ b4,
    const float* __restrict__ coef, const float* __restrict__ size_in,
    const float* __restrict__ treat,
    float* __restrict__ z_out, float* __restrict__ zdp_out,
    float* __restrict__ acc)
{
  __shared__ float sW2[64 * 129];
  __shared__ float sW3[32 * 65];
  __shared__ float sW4[96];
  __shared__ float sB2[64], sB3[32], sB4[3], sC[21];
  __shared__ float a1s[4 * 128], d1s[4 * 128];
  __shared__ float a2s[4 * 64],  d2s[4 * 64];
  __shared__ float a3s[4 * 32],  d3s[4 * 32];
  __shared__ float zs[12], zds[12];
  __shared__ float rowl[4][3];
  const int t = threadIdx.x;
  for (int i = t; i < 64 * 128; i += 256) sW2[(i >> 7) * 129 + (i & 127)] = W2[i];
  for (int i = t; i < 32 * 64;  i += 256) sW3[(i >> 6) * 65  + (i & 63)]  = W3[i];
  if (t < 96) sW4[t] = W4[t];
  if (t < 64) sB2[t] = b2[t];
  if (t < 32) sB3[t] = b3[t];
  if (t < 3)  sB4[t] = b4[t];
  if (t < 21) sC[t]  = coef[t];
  const int r0 = blockIdx.x * 4;
  for (int i = t; i < 4 * 128; i += 256) {
    a1s[i] = a1 [(size_t)r0 * 128 + i];
    d1s[i] = dz1[(size_t)r0 * 128 + i];
  }
  __syncthreads();
  // layer 2 (128 -> 64)
  {
    const int r = t >> 6, o = t & 63;
    float p = 0.f, g = 0.f;
#pragma unroll 8
    for (int k = 0; k < 128; ++k) {
      float w = sW2[o * 129 + k];
      p = fmaf(w, a1s[r * 128 + k], p);
      g = fmaf(w, d1s[r * 128 + k], g);
    }
    float a = sigm(p + sB2[o]);
    a2s[r * 64 + o] = a;
    d2s[r * 64 + o] = a * (1.f - a) * g;
  }
  __syncthreads();
  // layer 3 (64 -> 32)
  if (t < 128) {
    const int r = t >> 5, o = t & 31;
    float p = 0.f, g = 0.f;
#pragma unroll
    for (int k = 0; k < 64; ++k) {
      float w = sW3[o * 65 + k];
      p = fmaf(w, a2s[r * 64 + k], p);
      g = fmaf(w, d2s[r * 64 + k], g);
    }
    float a = sigm(p + sB3[o]);
    a3s[r * 32 + o] = a;
    d3s[r * 32 + o] = a * (1.f - a) * g;
  }
  __syncthreads();
  // layer 4 (32 -> 3): z, z_dot_true
  if (t < 12) {
    const int r = t / 3, j = t % 3;
    float p = 0.f, g = 0.f;
#pragma unroll
    for (int k = 0; k < 32; ++k) {
      float w = sW4[j * 32 + k];
      p = fmaf(w, a3s[r * 32 + k], p);
      g = fmaf(w, d3s[r * 32 + k], g);
    }
    float zv = p + sB4[j];
    zs [r * 3 + j] = zv;
    zds[r * 3 + j] = g;
    z_out[(size_t)(r0 + r) * 3 + j] = zv;
  }
  __syncthreads();
  // theta @ coefficients, per-row losses
  if (t < 4) {
    const int r = t;
    float s = zs[r * 3 + 0], d = zs[r * 3 + 1], tt = zs[r * 3 + 2];
    float th[7] = {1.f, s, s * s, s * d, s * tt, s * s * d, s * s * tt};
    float sz = 0.f;
    for (int j = 0; j < 3; ++j) {
      float zp = 0.f;
#pragma unroll
      for (int i = 0; i < 7; ++i) zp = fmaf(th[i], sC[i * 3 + j], zp);
      zdp_out[(size_t)(r0 + r) * 3 + j] = zp;
      float e = zds[r * 3 + j] - zp;
      sz += e * e;
    }
    float e0 = s - size_in[r0 + r];
    float logit = tt;
    float trv = treat[r0 + r];
    float lt = fmaxf(logit, 0.f) + log1pf(expf(-fabsf(logit))) - logit * trv;
    rowl[r][0] = e0 * e0; rowl[r][1] = lt; rowl[r][2] = sz;
  }
  __syncthreads();
  if (t == 0) {
    float s0 = 0, s1 = 0, s2 = 0;
    for (int r = 0; r < 4; ++r) { s0 += rowl[r][0]; s1 += rowl[r][1]; s2 += rowl[r][2]; }
    atomicAdd(&acc[0], s0);
    atomicAdd(&acc[1], s1);
    atomicAdd(&acc[4], s2);
  }
}

// ---------------------------------------------------------------------------
// K3: decoder layers 1-3 forward + chain derivative -> h3, g3 (=dzd3)
// ---------------------------------------------------------------------------
__global__ __launch_bounds__(256) void dec_small_kernel(
    const float* __restrict__ z_in, const float* __restrict__ zdp,
    const float* __restrict__ W1, const float* __restrict__ b1,
    const float* __restrict__ W2, const float* __restrict__ b2,
    const float* __restrict__ W3, const float* __restrict__ b3,
    float* __restrict__ h3, float* __restrict__ g3)
{
  __shared__ float sW1[96], sB1[32];
  __shared__ float sW2[64 * 33], sB2[64];
  __shared__ float sW3[128 * 65], sB3[128];
  __shared__ float zr[12], zp[12];
  __shared__ float h1s[4 * 32], g1s[4 * 32];
  __shared__ float h2s[4 * 64], g2s[4 * 64];
  const int t = threadIdx.x;
  for (int i = t; i < 64 * 32;  i += 256) sW2[(i >> 5) * 33 + (i & 31)] = W2[i];
  for (int i = t; i < 128 * 64; i += 256) sW3[(i >> 6) * 65 + (i & 63)] = W3[i];
  if (t < 96)  sW1[t] = W1[t];
  if (t < 32)  sB1[t] = b1[t];
  if (t < 64)  sB2[t] = b2[t];
  if (t < 128) sB3[t] = b3[t];
  const int r0 = blockIdx.x * 4;
  if (t < 12) { zr[t] = z_in[(size_t)r0 * 3 + t]; zp[t] = zdp[(size_t)r0 * 3 + t]; }
  __syncthreads();
  // layer 1 (3 -> 32)
  if (t < 128) {
    const int r = t >> 5, o = t & 31;
    float p = sB1[o], g = 0.f;
#pragma unroll
    for (int k = 0; k < 3; ++k) {
      float w = sW1[o * 3 + k];
      p = fmaf(w, zr[r * 3 + k], p);
      g = fmaf(w, zp[r * 3 + k], g);
    }
    float h = sigm(p);
    h1s[r * 32 + o] = h; g1s[r * 32 + o] = h * (1.f - h) * g;
  }
  __syncthreads();
  // layer 2 (32 -> 64)
  {
    const int r = t >> 6, o = t & 63;
    float p = sB2[o], g = 0.f;
#pragma unroll
    for (int k = 0; k < 32; ++k) {
      float w = sW2[o * 33 + k];
      p = fmaf(w, h1s[r * 32 + k], p);
      g = fmaf(w, g1s[r * 32 + k], g);
    }
    float h = sigm(p);
    h2s[r * 64 + o] = h; g2s[r * 64 + o] = h * (1.f - h) * g;
  }
  __syncthreads();
  // layer 3 (64 -> 128)
  {
    const int r = t >> 6;
    const int ob = t & 63;
#pragma unroll
    for (int c = 0; c < 2; ++c) {
      const int o = ob + 64 * c;
      float p = sB3[o], g = 0.f;
#pragma unroll
      for (int k = 0; k < 64; ++k) {
        float w = sW3[o * 65 + k];
        p = fmaf(w, h2s[r * 64 + k], p);
        g = fmaf(w, g2s[r * 64 + k], g);
      }
      float h = sigm(p);
      h3[(size_t)(r0 + r) * 128 + o] = h;
      g3[(size_t)(r0 + r) * 128 + o] = h * (1.f - h) * g;
    }
  }
}

// ---------------------------------------------------------------------------
// K4: x_hat = h3@dW4.T + db4 (written to out); x_dot_pred = g3@dW4.T (not
// materialized); fused recon/sindy_x squared-error reduction.
// BM=32 x BN=64, K=128 fully staged. 256 threads, TM=2 x TN=4.
// ---------------------------------------------------------------------------
__global__ __launch_bounds__(256) void dec4_kernel(
    const float* __restrict__ h3, const float* __restrict__ g3,
    const float* __restrict__ W, const float* __restrict__ bias,
    const float* __restrict__ x, const float* __restrict__ xd,
    float* __restrict__ xhat, float* __restrict__ acc)
{
  __shared__ float Hs[32 * 132];
  __shared__ float Gs[32 * 132];
  __shared__ float Ws[64 * 132];
  __shared__ float red[8];
  const int t = threadIdx.x;
  const int r0 = blockIdx.y * 32;
  const int c0 = blockIdx.x * 64;
#pragma unroll
  for (int i = 0; i < 4; ++i) {
    int lin4 = i * 256 + t;                 // 0..1023 float4s
    int row = lin4 >> 5, koff = (lin4 & 31) * 4;
    float4 hv = *(const float4*)&h3[(size_t)r0 * 128 + (size_t)lin4 * 4];
    float4 gv = *(const float4*)&g3[(size_t)r0 * 128 + (size_t)lin4 * 4];
    *(float4*)&Hs[row * 132 + koff] = hv;
    *(float4*)&Gs[row * 132 + koff] = gv;
  }
#pragma unroll
  for (int i = 0; i < 8; ++i) {
    int lin4 = i * 256 + t;                 // 0..2047 float4s
    int n = lin4 >> 5, koff = (lin4 & 31) * 4;
    *(float4*)&Ws[n * 132 + koff] = *(const float4*)&W[(size_t)c0 * 128 + (size_t)lin4 * 4];
  }
  __syncthreads();
  const int ty = t >> 4, tx = t & 15;
  float ap[2][4] = {{0.f}};
  float ag[2][4] = {{0.f}};
#pragma unroll 8
  for (int k4 = 0; k4 < 32; ++k4) {
    float4 hv[2], gv[2], wv[4];
#pragma unroll
    for (int i = 0; i < 2; ++i) {
      hv[i] = *(const float4*)&Hs[(ty * 2 + i) * 132 + k4 * 4];
      gv[i] = *(const float4*)&Gs[(ty * 2 + i) * 132 + k4 * 4];
    }
#pragma unroll
    for (int j = 0; j < 4; ++j)
      wv[j] = *(const float4*)&Ws[(tx + 16 * j) * 132 + k4 * 4];
#pragma unroll
    for (int i = 0; i < 2; ++i)
#pragma unroll
      for (int j = 0; j < 4; ++j) {
        ap[i][j] = fmaf(hv[i].x, wv[j].x, ap[i][j]);
        ap[i][j] = fmaf(hv[i].y, wv[j].y, ap[i][j]);
        ap[i][j] = fmaf(hv[i].z, wv[j].z, ap[i][j]);
        ap[i][j] = fmaf(hv[i].w, wv[j].w, ap[i][j]);
        ag[i][j] = fmaf(gv[i].x, wv[j].x, ag[i][j]);
        ag[i][j] = fmaf(gv[i].y, wv[j].y, ag[i][j]);
        ag[i][j] = fmaf(gv[i].z, wv[j].z, ag[i][j]);
        ag[i][j] = fmaf(gv[i].w, wv[j].w, ag[i][j]);
      }
  }
  float rsum = 0.f, ssum = 0.f;
#pragma unroll
  for (int i = 0; i < 2; ++i) {
    const int row = r0 + ty * 2 + i;
#pragma unroll
    for (int j = 0; j < 4; ++j) {
      const int col = c0 + tx + 16 * j;
      float xh = ap[i][j] + bias[col];
      xhat[(size_t)row * 2048 + col] = xh;
      float ex = x[(size_t)row * 2048 + col] - xh;
      rsum = fmaf(ex, ex, rsum);
      float ed = xd[(size_t)row * 2048 + col] - ag[i][j];
      ssum = fmaf(ed, ed, ssum);
    }
  }
#pragma unroll
  for (int off = 32; off > 0; off >>= 1) {
    rsum += __shfl_down(rsum, off);
    ssum += __shfl_down(ssum, off);
  }
  if ((t & 63) == 0) { red[(t >> 6) * 2] = rsum; red[(t >> 6) * 2 + 1] = ssum; }
  __syncthreads();
  if (t == 0) {
    float a = red[0] + red[2] + red[4] + red[6];
    float b = red[1] + red[3] + red[5] + red[7];
    atomicAdd(&acc[2], a);
    atomicAdd(&acc[3], b);
  }
}

// ---------------------------------------------------------------------------
// K5: write the 6 scalar outputs
// ---------------------------------------------------------------------------
__global__ void finalize_kernel(const float* __restrict__ acc,
                                const float* __restrict__ coef,
                                float* __restrict__ outp)
{
  if (threadIdx.x == 0 && blockIdx.x == 0) {
    outp[0] = acc[0] * (1.0f / 16384.0f);            // loss_po
    outp[1] = acc[1] * (1.0f / 16384.0f);            // loss_tr
    outp[2] = acc[2] * (1.0f / 33554432.0f);         // recon
    outp[3] = acc[3] * (1.0f / 33554432.0f);         // sindy_x
    outp[4] = acc[4] * (1.0f / 49152.0f);            // sindy_z
    float s = 0.f;
    for (int i = 0; i < 21; ++i) s += fabsf(coef[i]);
    outp[5] = s * (1.0f / 21.0f);                    // l1
  }
}

extern "C" void kernel_launch(void* const* d_in, const int* in_sizes, int n_in,
                              void* d_out, int out_size, void* d_ws, size_t ws_size,
                              hipStream_t stream) {
  (void)in_sizes; (void)n_in; (void)out_size; (void)ws_size;
  const float* x    = (const float*)d_in[0];
  const float* xd   = (const float*)d_in[1];
  const float* tr   = (const float*)d_in[2];
  const float* sz   = (const float*)d_in[3];
  const float* eW1  = (const float*)d_in[4];
  const float* eb1  = (const float*)d_in[5];
  const float* eW2  = (const float*)d_in[6];
  const float* eb2  = (const float*)d_in[7];
  const float* eW3  = (const float*)d_in[8];
  const float* eb3  = (const float*)d_in[9];
  const float* eW4  = (const float*)d_in[10];
  const float* eb4  = (const float*)d_in[11];
  const float* dW1  = (const float*)d_in[12];
  const float* db1  = (const float*)d_in[13];
  const float* dW2  = (const float*)d_in[14];
  const float* db2  = (const float*)d_in[15];
  const float* dW3  = (const float*)d_in[16];
  const float* db3  = (const float*)d_in[17];
  const float* dW4  = (const float*)d_in[18];
  const float* db4  = (const float*)d_in[19];
  const float* coef = (const float*)d_in[20];

  float* ws  = (float*)d_ws;
  float* a1  = ws;                    // 16384*128
  float* dz1 = ws + 2097152;          // 16384*128
  float* h3  = ws + 4194304;          // 16384*128
  float* g3  = ws + 6291456;          // 16384*128
  float* zdp = ws + 8388608;          // 16384*3
  float* acc = ws + 8437760;          // 8 floats

  float* z_out = (float*)d_out;                         // 16384*3
  float* xhat  = (float*)d_out + 49152;                 // 16384*2048
  float* scal  = (float*)d_out + 49152 + 33554432;      // 6 scalars

  hipMemsetAsync(acc, 0, 8 * sizeof(float), stream);

  enc1_kernel<<<512, 256, 0, stream>>>(x, xd, tr, eW1, eb1, a1, dz1);
  enc_small_kernel<<<4096, 256, 0, stream>>>(a1, dz1, eW2, eb2, eW3, eb3, eW4, eb4,
                                             coef, sz, tr, z_out, zdp, acc);
  dec_small_kernel<<<4096, 256, 0, stream>>>(z_out, zdp, dW1, db1, dW2, db2, dW3, db3,
                                             h3, g3);
  dim3 g4(32, 512);
  dec4_kernel<<<g4, 256, 0, stream>>>(h3, g3, dW4, db4, x, xd, xhat, acc);
  finalize_kernel<<<1, 64, 0, stream>>>(acc, coef, scal);
}

// Round 2
// 809.575 us; speedup vs baseline: 1.6146x; 1.6146x over previous
//
#include <hip/hip_runtime.h>
#include <hip/hip_bf16.h>
#include <math.h>

typedef __attribute__((ext_vector_type(8))) short short8;
typedef __attribute__((ext_vector_type(4))) float f32x4;

__device__ __forceinline__ float sigm(float v) { return 1.0f / (1.0f + expf(-v)); }
__device__ __forceinline__ unsigned short f2b(float f) {
  __hip_bfloat16 h = __float2bfloat16(f);
  return __builtin_bit_cast(unsigned short, h);
}

// ---------------------------------------------------------------------------
// K0: pre-convert eW1[:, :2048] -> Wb1 bf16 [128][2048], dW4 -> Wb4 bf16 [2048][128]
// ---------------------------------------------------------------------------
__global__ __launch_bounds__(256) void wcvt_kernel(
    const float* __restrict__ eW1, const float* __restrict__ dW4,
    unsigned short* __restrict__ Wb1, unsigned short* __restrict__ Wb4)
{
  int idx = blockIdx.x * 256 + threadIdx.x;   // 0..262143
  int o = idx >> 11, k = idx & 2047;
  Wb1[idx] = f2b(eW1[(size_t)o * 2049 + k]);
  Wb4[idx] = f2b(dW4[idx]);
}

// ---------------------------------------------------------------------------
// K1: MFMA dual GEMM: accx = x@W.T, accd = xd@W.T (bf16, fp32 acc)
// epilogue adds treatment*wlast + bias, sigmoid -> a1; dz1 = a1(1-a1)*g
// BM=32 rows (both streams), BN=128 (all outs), BK=64, 256 thr = 4 waves.
// ---------------------------------------------------------------------------
__global__ __launch_bounds__(256, 2) void enc1_mfma(
    const float* __restrict__ x, const float* __restrict__ xd,
    const float* __restrict__ tr, const unsigned short* __restrict__ Wb,
    const float* __restrict__ Wfull, const float* __restrict__ bias,
    float* __restrict__ a1, float* __restrict__ dz1)
{
  __shared__ unsigned short As[32 * 72];
  __shared__ unsigned short Ds[32 * 72];
  __shared__ unsigned short Ws[128 * 72];
  const int t = threadIdx.x;
  const int w = t >> 6;          // wave 0..3
  const int L = t & 63;
  const int q = L >> 4;          // quad 0..3
  const int ln = L & 15;
  const int r0 = blockIdx.x * 32;

  f32x4 accx[2][2], accd[2][2];
#pragma unroll
  for (int m = 0; m < 2; ++m)
#pragma unroll
    for (int n = 0; n < 2; ++n) {
      accx[m][n] = (f32x4){0.f, 0.f, 0.f, 0.f};
      accd[m][n] = (f32x4){0.f, 0.f, 0.f, 0.f};
    }

  for (int kt = 0; kt < 32; ++kt) {
    const int kb = kt * 64;
    // stage A (x) and D (xd): 32 rows x 64 k, fp32 -> bf16
#pragma unroll
    for (int i = 0; i < 2; ++i) {
      int lin = i * 256 + t;            // 0..511
      int ar = lin >> 4;                // 0..31
      int kc = (lin & 15) * 4;          // 0..60
      float4 xv = *(const float4*)&x [(size_t)(r0 + ar) * 2048 + kb + kc];
      float4 dv = *(const float4*)&xd[(size_t)(r0 + ar) * 2048 + kb + kc];
      ushort4 xs = {f2b(xv.x), f2b(xv.y), f2b(xv.z), f2b(xv.w)};
      ushort4 ds = {f2b(dv.x), f2b(dv.y), f2b(dv.z), f2b(dv.w)};
      *(ushort4*)&As[ar * 72 + kc] = xs;
      *(ushort4*)&Ds[ar * 72 + kc] = ds;
    }
    // stage W: 128 rows x 64 k bf16 (16B chunks)
#pragma unroll
    for (int i = 0; i < 4; ++i) {
      int lin = i * 256 + t;            // 0..1023
      int wr = lin >> 3;                // 0..127
      int kc8 = (lin & 7) * 8;          // 0..56
      *(uint4*)&Ws[wr * 72 + kc8] =
          *(const uint4*)&Wb[(size_t)wr * 2048 + kb + kc8];
    }
    __syncthreads();
#pragma unroll
    for (int ks = 0; ks < 2; ++ks) {
      const int ko = ks * 32 + q * 8;
      short8 ax[2], ad[2], bw[2];
#pragma unroll
      for (int m = 0; m < 2; ++m) {
        ax[m] = *(const short8*)&As[(m * 16 + ln) * 72 + ko];
        ad[m] = *(const short8*)&Ds[(m * 16 + ln) * 72 + ko];
      }
#pragma unroll
      for (int n = 0; n < 2; ++n)
        bw[n] = *(const short8*)&Ws[(w * 32 + n * 16 + ln) * 72 + ko];
#pragma unroll
      for (int m = 0; m < 2; ++m)
#pragma unroll
        for (int n = 0; n < 2; ++n) {
          accx[m][n] = __builtin_amdgcn_mfma_f32_16x16x32_bf16(ax[m], bw[n], accx[m][n], 0, 0, 0);
          accd[m][n] = __builtin_amdgcn_mfma_f32_16x16x32_bf16(ad[m], bw[n], accd[m][n], 0, 0, 0);
        }
    }
    __syncthreads();
  }
  // epilogue: C[row = m*16 + q*4 + r][col = w*32 + n*16 + ln]
#pragma unroll
  for (int m = 0; m < 2; ++m) {
#pragma unroll
    for (int r = 0; r < 4; ++r) {
      const int row = r0 + m * 16 + q * 4 + r;
      const float trv = tr[row];
#pragma unroll
      for (int n = 0; n < 2; ++n) {
        const int col = w * 32 + n * 16 + ln;
        const float wl = Wfull[(size_t)col * 2049 + 2048];
        float p = accx[m][n][r] + trv * wl + bias[col];
        float g = accd[m][n][r] + trv * wl;
        float a = sigm(p);
        a1 [(size_t)row * 128 + col] = a;
        dz1[(size_t)row * 128 + col] = a * (1.f - a) * g;
      }
    }
  }
}

// ---------------------------------------------------------------------------
// K2: encoder layers 2-4 + z, z_dot_true, z_dot_pred, loss_po/loss_tr/sindy_z
// ---------------------------------------------------------------------------
__global__ __launch_bounds__(256) void enc_small_kernel(
    const float* __restrict__ a1, const float* __restrict__ dz1,
    const float* __restrict__ W2, const float* __restrict__ b2,
    const float* __restrict__ W3, const float* __restrict__ b3,
    const float* __restrict__ W4, const float* __restrict__ b4,
    const float* __restrict__ coef, const float* __restrict__ size_in,
    const float* __restrict__ treat,
    float* __restrict__ z_out, float* __restrict__ zdp_out,
    float* __restrict__ acc)
{
  __shared__ float sW2[64 * 129];
  __shared__ float sW3[32 * 65];
  __shared__ float sW4[96];
  __shared__ float sB2[64], sB3[32], sB4[3], sC[21];
  __shared__ float a1s[4 * 128], d1s[4 * 128];
  __shared__ float a2s[4 * 64],  d2s[4 * 64];
  __shared__ float a3s[4 * 32],  d3s[4 * 32];
  __shared__ float zs[12], zds[12];
  __shared__ float rowl[4][3];
  const int t = threadIdx.x;
  for (int i = t; i < 64 * 128; i += 256) sW2[(i >> 7) * 129 + (i & 127)] = W2[i];
  for (int i = t; i < 32 * 64;  i += 256) sW3[(i >> 6) * 65  + (i & 63)]  = W3[i];
  if (t < 96) sW4[t] = W4[t];
  if (t < 64) sB2[t] = b2[t];
  if (t < 32) sB3[t] = b3[t];
  if (t < 3)  sB4[t] = b4[t];
  if (t < 21) sC[t]  = coef[t];
  const int r0 = blockIdx.x * 4;
  for (int i = t; i < 4 * 128; i += 256) {
    a1s[i] = a1 [(size_t)r0 * 128 + i];
    d1s[i] = dz1[(size_t)r0 * 128 + i];
  }
  __syncthreads();
  {
    const int r = t >> 6, o = t & 63;
    float p = 0.f, g = 0.f;
#pragma unroll 8
    for (int k = 0; k < 128; ++k) {
      float w = sW2[o * 129 + k];
      p = fmaf(w, a1s[r * 128 + k], p);
      g = fmaf(w, d1s[r * 128 + k], g);
    }
    float a = sigm(p + sB2[o]);
    a2s[r * 64 + o] = a;
    d2s[r * 64 + o] = a * (1.f - a) * g;
  }
  __syncthreads();
  if (t < 128) {
    const int r = t >> 5, o = t & 31;
    float p = 0.f, g = 0.f;
#pragma unroll
    for (int k = 0; k < 64; ++k) {
      float w = sW3[o * 65 + k];
      p = fmaf(w, a2s[r * 64 + k], p);
      g = fmaf(w, d2s[r * 64 + k], g);
    }
    float a = sigm(p + sB3[o]);
    a3s[r * 32 + o] = a;
    d3s[r * 32 + o] = a * (1.f - a) * g;
  }
  __syncthreads();
  if (t < 12) {
    const int r = t / 3, j = t % 3;
    float p = 0.f, g = 0.f;
#pragma unroll
    for (int k = 0; k < 32; ++k) {
      float w = sW4[j * 32 + k];
      p = fmaf(w, a3s[r * 32 + k], p);
      g = fmaf(w, d3s[r * 32 + k], g);
    }
    float zv = p + sB4[j];
    zs [r * 3 + j] = zv;
    zds[r * 3 + j] = g;
    z_out[(size_t)(r0 + r) * 3 + j] = zv;
  }
  __syncthreads();
  if (t < 4) {
    const int r = t;
    float s = zs[r * 3 + 0], d = zs[r * 3 + 1], tt = zs[r * 3 + 2];
    float th[7] = {1.f, s, s * s, s * d, s * tt, s * s * d, s * s * tt};
    float sz = 0.f;
    for (int j = 0; j < 3; ++j) {
      float zp = 0.f;
#pragma unroll
      for (int i = 0; i < 7; ++i) zp = fmaf(th[i], sC[i * 3 + j], zp);
      zdp_out[(size_t)(r0 + r) * 3 + j] = zp;
      float e = zds[r * 3 + j] - zp;
      sz += e * e;
    }
    float e0 = s - size_in[r0 + r];
    float logit = tt;
    float trv = treat[r0 + r];
    float lt = fmaxf(logit, 0.f) + log1pf(expf(-fabsf(logit))) - logit * trv;
    rowl[r][0] = e0 * e0; rowl[r][1] = lt; rowl[r][2] = sz;
  }
  __syncthreads();
  if (t == 0) {
    float s0 = 0, s1 = 0, s2 = 0;
    for (int r = 0; r < 4; ++r) { s0 += rowl[r][0]; s1 += rowl[r][1]; s2 += rowl[r][2]; }
    atomicAdd(&acc[0], s0);
    atomicAdd(&acc[1], s1);
    atomicAdd(&acc[4], s2);
  }
}

// ---------------------------------------------------------------------------
// K3: decoder layers 1-3 forward + chain derivative -> h3b, g3b (bf16)
// ---------------------------------------------------------------------------
__global__ __launch_bounds__(256) void dec_small_kernel(
    const float* __restrict__ z_in, const float* __restrict__ zdp,
    const float* __restrict__ W1, const float* __restrict__ b1,
    const float* __restrict__ W2, const float* __restrict__ b2,
    const float* __restrict__ W3, const float* __restrict__ b3,
    unsigned short* __restrict__ h3b, unsigned short* __restrict__ g3b)
{
  __shared__ float sW1[96], sB1[32];
  __shared__ float sW2[64 * 33], sB2[64];
  __shared__ float sW3[128 * 65], sB3[128];
  __shared__ float zr[12], zp[12];
  __shared__ float h1s[4 * 32], g1s[4 * 32];
  __shared__ float h2s[4 * 64], g2s[4 * 64];
  const int t = threadIdx.x;
  for (int i = t; i < 64 * 32;  i += 256) sW2[(i >> 5) * 33 + (i & 31)] = W2[i];
  for (int i = t; i < 128 * 64; i += 256) sW3[(i >> 6) * 65 + (i & 63)] = W3[i];
  if (t < 96)  sW1[t] = W1[t];
  if (t < 32)  sB1[t] = b1[t];
  if (t < 64)  sB2[t] = b2[t];
  if (t < 128) sB3[t] = b3[t];
  const int r0 = blockIdx.x * 4;
  if (t < 12) { zr[t] = z_in[(size_t)r0 * 3 + t]; zp[t] = zdp[(size_t)r0 * 3 + t]; }
  __syncthreads();
  if (t < 128) {
    const int r = t >> 5, o = t & 31;
    float p = sB1[o], g = 0.f;
#pragma unroll
    for (int k = 0; k < 3; ++k) {
      float w = sW1[o * 3 + k];
      p = fmaf(w, zr[r * 3 + k], p);
      g = fmaf(w, zp[r * 3 + k], g);
    }
    float h = sigm(p);
    h1s[r * 32 + o] = h; g1s[r * 32 + o] = h * (1.f - h) * g;
  }
  __syncthreads();
  {
    const int r = t >> 6, o = t & 63;
    float p = sB2[o], g = 0.f;
#pragma unroll
    for (int k = 0; k < 32; ++k) {
      float w = sW2[o * 33 + k];
      p = fmaf(w, h1s[r * 32 + k], p);
      g = fmaf(w, g1s[r * 32 + k], g);
    }
    float h = sigm(p);
    h2s[r * 64 + o] = h; g2s[r * 64 + o] = h * (1.f - h) * g;
  }
  __syncthreads();
  {
    const int r = t >> 6;
    const int ob = t & 63;
#pragma unroll
    for (int c = 0; c < 2; ++c) {
      const int o = ob + 64 * c;
      float p = sB3[o], g = 0.f;
#pragma unroll
      for (int k = 0; k < 64; ++k) {
        float w = sW3[o * 65 + k];
        p = fmaf(w, h2s[r * 64 + k], p);
        g = fmaf(w, g2s[r * 64 + k], g);
      }
      float h = sigm(p);
      h3b[(size_t)(r0 + r) * 128 + o] = f2b(h);
      g3b[(size_t)(r0 + r) * 128 + o] = f2b(h * (1.f - h) * g);
    }
  }
}

// ---------------------------------------------------------------------------
// K4: MFMA dual GEMM: xhat = h3@W4.T + b (fp32 out), xdp = g3@W4.T
// fused recon/sindy_x reduction. BM=32, BN=128, K=128 (2 stages of 64).
// ---------------------------------------------------------------------------
__global__ __launch_bounds__(256, 2) void dec4_mfma(
    const unsigned short* __restrict__ h3b, const unsigned short* __restrict__ g3b,
    const unsigned short* __restrict__ Wb, const float* __restrict__ bias,
    const float* __restrict__ x, const float* __restrict__ xd,
    float* __restrict__ xhat, float* __restrict__ acc)
{
  __shared__ unsigned short Hs[32 * 72];
  __shared__ unsigned short Gs[32 * 72];
  __shared__ unsigned short Ws[128 * 72];
  __shared__ float red[8];
  const int t = threadIdx.x;
  const int w = t >> 6;
  const int L = t & 63;
  const int q = L >> 4;
  const int ln = L & 15;
  const int r0 = blockIdx.x * 32;
  const int c0 = blockIdx.y * 128;

  f32x4 accH[2][2], accG[2][2];
#pragma unroll
  for (int m = 0; m < 2; ++m)
#pragma unroll
    for (int n = 0; n < 2; ++n) {
      accH[m][n] = (f32x4){0.f, 0.f, 0.f, 0.f};
      accG[m][n] = (f32x4){0.f, 0.f, 0.f, 0.f};
    }

  for (int kt = 0; kt < 2; ++kt) {
    const int kb = kt * 64;
    {
      int hr = t >> 3;               // 0..31
      int kc8 = (t & 7) * 8;         // 0..56
      *(uint4*)&Hs[hr * 72 + kc8] = *(const uint4*)&h3b[(size_t)(r0 + hr) * 128 + kb + kc8];
      *(uint4*)&Gs[hr * 72 + kc8] = *(const uint4*)&g3b[(size_t)(r0 + hr) * 128 + kb + kc8];
    }
#pragma unroll
    for (int i = 0; i < 4; ++i) {
      int lin = i * 256 + t;
      int wr = lin >> 3;             // 0..127
      int kc8 = (lin & 7) * 8;
      *(uint4*)&Ws[wr * 72 + kc8] = *(const uint4*)&Wb[(size_t)(c0 + wr) * 128 + kb + kc8];
    }
    __syncthreads();
#pragma unroll
    for (int ks = 0; ks < 2; ++ks) {
      const int ko = ks * 32 + q * 8;
      short8 ah[2], ag[2], bw[2];
#pragma unroll
      for (int m = 0; m < 2; ++m) {
        ah[m] = *(const short8*)&Hs[(m * 16 + ln) * 72 + ko];
        ag[m] = *(const short8*)&Gs[(m * 16 + ln) * 72 + ko];
      }
#pragma unroll
      for (int n = 0; n < 2; ++n)
        bw[n] = *(const short8*)&Ws[(w * 32 + n * 16 + ln) * 72 + ko];
#pragma unroll
      for (int m = 0; m < 2; ++m)
#pragma unroll
        for (int n = 0; n < 2; ++n) {
          accH[m][n] = __builtin_amdgcn_mfma_f32_16x16x32_bf16(ah[m], bw[n], accH[m][n], 0, 0, 0);
          accG[m][n] = __builtin_amdgcn_mfma_f32_16x16x32_bf16(ag[m], bw[n], accG[m][n], 0, 0, 0);
        }
    }
    __syncthreads();
  }
  float rsum = 0.f, ssum = 0.f;
#pragma unroll
  for (int m = 0; m < 2; ++m) {
#pragma unroll
    for (int r = 0; r < 4; ++r) {
      const int row = r0 + m * 16 + q * 4 + r;
#pragma unroll
      for (int n = 0; n < 2; ++n) {
        const int col = c0 + w * 32 + n * 16 + ln;
        float xh = accH[m][n][r] + bias[col];
        xhat[(size_t)row * 2048 + col] = xh;
        float ex = x[(size_t)row * 2048 + col] - xh;
        rsum = fmaf(ex, ex, rsum);
        float ed = xd[(size_t)row * 2048 + col] - accG[m][n][r];
        ssum = fmaf(ed, ed, ssum);
      }
    }
  }
#pragma unroll
  for (int off = 32; off > 0; off >>= 1) {
    rsum += __shfl_down(rsum, off);
    ssum += __shfl_down(ssum, off);
  }
  if ((t & 63) == 0) { red[(t >> 6) * 2] = rsum; red[(t >> 6) * 2 + 1] = ssum; }
  __syncthreads();
  if (t == 0) {
    float a = red[0] + red[2] + red[4] + red[6];
    float b = red[1] + red[3] + red[5] + red[7];
    atomicAdd(&acc[2], a);
    atomicAdd(&acc[3], b);
  }
}

// ---------------------------------------------------------------------------
// K5: write the 6 scalar outputs
// ---------------------------------------------------------------------------
__global__ void finalize_kernel(const float* __restrict__ acc,
                                const float* __restrict__ coef,
                                float* __restrict__ outp)
{
  if (threadIdx.x == 0 && blockIdx.x == 0) {
    outp[0] = acc[0] * (1.0f / 16384.0f);            // loss_po
    outp[1] = acc[1] * (1.0f / 16384.0f);            // loss_tr
    outp[2] = acc[2] * (1.0f / 33554432.0f);         // recon
    outp[3] = acc[3] * (1.0f / 33554432.0f);         // sindy_x
    outp[4] = acc[4] * (1.0f / 49152.0f);            // sindy_z
    float s = 0.f;
    for (int i = 0; i < 21; ++i) s += fabsf(coef[i]);
    outp[5] = s * (1.0f / 21.0f);                    // l1
  }
}

extern "C" void kernel_launch(void* const* d_in, const int* in_sizes, int n_in,
                              void* d_out, int out_size, void* d_ws, size_t ws_size,
                              hipStream_t stream) {
  (void)in_sizes; (void)n_in; (void)out_size; (void)ws_size;
  const float* x    = (const float*)d_in[0];
  const float* xd   = (const float*)d_in[1];
  const float* tr   = (const float*)d_in[2];
  const float* sz   = (const float*)d_in[3];
  const float* eW1  = (const float*)d_in[4];
  const float* eb1  = (const float*)d_in[5];
  const float* eW2  = (const float*)d_in[6];
  const float* eb2  = (const float*)d_in[7];
  const float* eW3  = (const float*)d_in[8];
  const float* eb3  = (const float*)d_in[9];
  const float* eW4  = (const float*)d_in[10];
  const float* eb4  = (const float*)d_in[11];
  const float* dW1  = (const float*)d_in[12];
  const float* db1  = (const float*)d_in[13];
  const float* dW2  = (const float*)d_in[14];
  const float* db2  = (const float*)d_in[15];
  const float* dW3  = (const float*)d_in[16];
  const float* db3  = (const float*)d_in[17];
  const float* dW4  = (const float*)d_in[18];
  const float* db4  = (const float*)d_in[19];
  const float* coef = (const float*)d_in[20];

  float* ws = (float*)d_ws;
  float* a1   = ws;                                   // 2097152 f32
  float* dz1  = ws + 2097152;                         // 2097152 f32
  float* zdp  = ws + 4194304;                         // 49152 f32
  float* acc  = ws + 4243456;                         // 8 f32 (16B aligned)
  unsigned short* h3b = (unsigned short*)(ws + 4243472);  // 2097152 bf16
  unsigned short* g3b = (unsigned short*)(ws + 5292048);  // 2097152 bf16
  unsigned short* Wb1 = (unsigned short*)(ws + 6340624);  // 262144 bf16
  unsigned short* Wb4 = (unsigned short*)(ws + 6471696);  // 262144 bf16

  float* z_out = (float*)d_out;                         // 16384*3
  float* xhat  = (float*)d_out + 49152;                 // 16384*2048
  float* scal  = (float*)d_out + 49152 + 33554432;      // 6 scalars

  hipMemsetAsync(acc, 0, 8 * sizeof(float), stream);

  wcvt_kernel<<<1024, 256, 0, stream>>>(eW1, dW4, Wb1, Wb4);
  enc1_mfma<<<512, 256, 0, stream>>>(x, xd, tr, Wb1, eW1, eb1, a1, dz1);
  enc_small_kernel<<<4096, 256, 0, stream>>>(a1, dz1, eW2, eb2, eW3, eb3, eW4, eb4,
                                             coef, sz, tr, z_out, zdp, acc);
  dec_small_kernel<<<4096, 256, 0, stream>>>(z_out, zdp, dW1, db1, dW2, db2, dW3, db3,
                                             h3b, g3b);
  dim3 g4(512, 16);
  dec4_mfma<<<g4, 256, 0, stream>>>(h3b, g3b, Wb4, db4, x, xd, xhat, acc);
  finalize_kernel<<<1, 64, 0, stream>>>(acc, coef, scal);
}